// Round 17
// baseline (128.568 us; speedup 1.0000x reference)
//
#include <hip/hip_runtime.h>
#include <hip/hip_bf16.h>
#include <math.h>

#define B_DIM 8192
#define IN_F  1024
#define OUT_F 1024
#define NSTEP 160                    // 32 g-groups x 5 slabs (K=5120)
#define BTILE 8192                   // one step-tile: 128 rows/cols x 32 k x 2B
#define NT    80                     // K-tiles per half (K-split 2)

typedef unsigned short u16;
typedef unsigned int u32;
typedef __attribute__((ext_vector_type(8))) short bf16x8;
typedef __attribute__((ext_vector_type(8))) unsigned short u16x8;
typedef __attribute__((ext_vector_type(4))) float f32x4;

#define GLOBAL_AS __attribute__((address_space(1)))
#define LDS_AS    __attribute__((address_space(3)))

__device__ __forceinline__ void gload16(const void* g, void* l) {
    __builtin_amdgcn_global_load_lds((const GLOBAL_AS unsigned int*)g,
                                     (LDS_AS unsigned int*)l, 16, 0, 0);
}

__device__ __forceinline__ u16 f2bf(float v) {
    u32 u = __float_as_uint(v);
    return (u16)((u + 0x7FFFu + ((u >> 16) & 1u)) >> 16);
}

__device__ __forceinline__ u32 cvt_pk(float lo, float hi) {
    u32 r;
    asm("v_cvt_pk_bf16_f32 %0, %1, %2" : "=v"(r) : "v"(lo), "v"(hi));
    return r;
}

// x-space step threshold for grid value gv: smallest f32 T with
// (x >= T) <=> ((double)x > atanh(midpoint(gv, prevfloat(gv)))) —
// replicates a correctly-rounded tanh's interval comparisons.
__device__ __forceinline__ float step_threshold(float gv) {
    float below = nextafterf(gv, -2.0f);
    double mid = 0.5 * ((double)gv + (double)below);
    double t = atanh(mid);
    float Tf = (float)t;
    if (!((double)Tf > t)) Tf = nextafterf(Tf, 3.0f);
    return Tf;
}

// ---------------------------------------------------------------------------
// prep kernel (R13 verbatim) — one launch, three sections by blockIdx:
//   bid 0..511    : pack_B  (8 panels x 128 cols; s=0 base_weight,
//                   s=1..4 bf16(sw_s - sw_{s-1}); tiles t = g*5 + s)
//   bid 512..767  : bias[o] = sum_i sw[o,i,0]
//   bid 768..4863 : pack_A  (64 panels x 128 rows; s=0 bf16(x),
//                   s=1..4 indicators 1[x >= T_s])
// Tile byte = ((panel*160 + t)*8192) + sub*1024 + lane*16 for both images.
// ---------------------------------------------------------------------------
__global__ __launch_bounds__(256) void prep_kernel(
    const float* __restrict__ x, const float* __restrict__ sw,
    const float* __restrict__ bw, const float* __restrict__ grid,
    char* __restrict__ At, char* __restrict__ Bt, float* __restrict__ biasT)
{
    int bid = blockIdx.x;
    int tid = threadIdx.x;

    if (bid < 512) {                                // ---- pack_B ----
        int gid  = bid * 256 + tid;
        int lane = gid & 63;
        int wav  = gid >> 6;
        int g    = wav & 31;
        int sn   = (wav >> 5) & 7;
        int p    = wav >> 8;                        // 0..7
        int fc   = lane & 15;
        int q    = lane >> 4;

        int o  = p * 128 + sn * 16 + fc;
        int i0 = g * 32 + q * 8;

        size_t tb = ((size_t)(p * NSTEP + g * 5)) * BTILE
                  + (size_t)sn * 1024 + (size_t)lane * 16;

        const float* bwr = bw + (size_t)o * IN_F + i0;
        float4 b0 = *(const float4*)bwr;
        float4 b1 = *(const float4*)(bwr + 4);
        float v[8] = {b0.x, b0.y, b0.z, b0.w, b1.x, b1.y, b1.z, b1.w};
        u16x8 s0;
        #pragma unroll
        for (int j = 0; j < 8; ++j) s0[j] = f2bf(v[j]);
        *(u16x8*)(Bt + tb) = s0;                    // s = 0

        float c[8][5];
        #pragma unroll
        for (int j = 0; j < 8; ++j) {
            const float* swr = sw + ((size_t)o * IN_F + i0 + j) * 8;
            float4 lo = *(const float4*)swr;
            float4 hi = *(const float4*)(swr + 4);
            c[j][0] = lo.x; c[j][1] = lo.y; c[j][2] = lo.z;
            c[j][3] = lo.w; c[j][4] = hi.x;
        }
        #pragma unroll
        for (int s = 1; s < 5; ++s) {
            u16x8 d;
            #pragma unroll
            for (int j = 0; j < 8; ++j) d[j] = f2bf(c[j][s] - c[j][s - 1]);
            *(u16x8*)(Bt + tb + (size_t)s * BTILE) = d;
        }
    } else if (bid < 768) {                         // ---- bias ----
        int o    = (bid - 512) * 4 + (tid >> 6);
        int lane = tid & 63;
        float s = 0.f;
        #pragma unroll
        for (int j = 0; j < 16; ++j)
            s += sw[((size_t)o * IN_F + j * 64 + lane) * 8];
        #pragma unroll
        for (int off = 32; off; off >>= 1)
            s += __shfl_down(s, off);
        if (lane == 0) biasT[o] = s;
    } else {                                        // ---- pack_A ----
        __shared__ float thr[4];
        if (tid == 0) {
            #pragma unroll
            for (int k = 0; k < 4; ++k)
                thr[k] = step_threshold(grid[k + 1]);   // -0.6,-0.2,0.2,0.6
        }
        __syncthreads();
        float T1 = thr[0], T2 = thr[1], T3 = thr[2], T4 = thr[3];

        int gid  = (bid - 768) * 256 + tid;         // 0 .. 1,048,575
        int lane = gid & 63;
        int wav  = gid >> 6;
        int g    = wav & 31;
        int sm   = (wav >> 5) & 7;
        int p    = wav >> 8;                        // 0..63
        int fr   = lane & 15;
        int q    = lane >> 4;

        int b  = p * 128 + sm * 16 + fr;
        int i0 = g * 32 + q * 8;

        const float* xr = x + (size_t)b * IN_F + i0;
        float4 a0 = *(const float4*)xr;
        float4 a1 = *(const float4*)(xr + 4);
        float v[8] = {a0.x, a0.y, a0.z, a0.w, a1.x, a1.y, a1.z, a1.w};

        size_t tb = ((size_t)(p * NSTEP + g * 5)) * BTILE
                  + (size_t)sm * 1024 + (size_t)lane * 16;

        {
            union { u32 u[4]; u16x8 s; } wpk;
            #pragma unroll
            for (int j = 0; j < 4; ++j) wpk.u[j] = cvt_pk(v[2*j], v[2*j+1]);
            *(u16x8*)(At + tb) = wpk.s;             // s = 0: bf16(x)
        }
        float T[4] = {T1, T2, T3, T4};
        #pragma unroll
        for (int s = 0; s < 4; ++s) {
            union { u32 u[4]; u16x8 t; } o;
            #pragma unroll
            for (int j = 0; j < 4; ++j)
                o.u[j] = (v[2*j]     >= T[s] ? 0x00003F80u : 0u)
                       | (v[2*j + 1] >= T[s] ? 0x3F800000u : 0u);
            *(u16x8*)(At + tb + (size_t)(s + 1) * BTILE) = o.t;
        }
    }
}

// ---------------------------------------------------------------------------
// GEMM half: R13's exact per-wave geometry (128x128 tile, 4 waves 2x2,
// 64x64/wave, 16 MFMA + 8 ds_read_b128 per tile, barrier-per-tile, counted
// vmcnt) with K-split 2: NT=80 tiles/block, 3-slot LDS ring (48 KB ->
// 3 blocks/CU, 12 waves/CU: other blocks' waves fill barrier bubbles).
// Depth-2 prefetch: top-of-iter vmcnt(4) drains stage(t), leaves stage(t+1);
// stage(t+2) issued after the barrier. vmcnt(0) only at the last tile.
// Grid 1024 = 64 brow x 8 bcol x 2 kh; tile = brow*16 + kh*8 + bcol,
// XCD-major: the 8 bcol-siblings of each (brow,kh) share one XCD's L2.
// kh=0 writes out (+bias); kh=1 writes bf16 partial to p1.
// ---------------------------------------------------------------------------
#define WAITV(N) asm volatile("s_waitcnt vmcnt(" #N ")" ::: "memory")

__global__ __launch_bounds__(256, 2) void gemm_half_kernel(
    const char* __restrict__ At, const char* __restrict__ Bt,
    const float* __restrict__ biasT, float* __restrict__ out,
    u16* __restrict__ p1)
{
    __shared__ __align__(16) char lds[3 * 16384];   // 3-slot ring, 48 KB

    int tid = threadIdx.x;
    int bid = blockIdx.x;                           // 0..1023

    int tile = (bid & 7) * 128 + (bid >> 3);        // XCD-major assignment
    int brow = tile >> 4;                           // 0..63
    int kh   = (tile >> 3) & 1;
    int bcol = tile & 7;                            // 0..7

    int lane = tid & 63;
    int w    = tid >> 6;
    int wr   = w >> 1;
    int wc   = w & 1;

    const char* Ap = At + ((size_t)brow * NSTEP + (size_t)kh * NT) * BTILE;
    const char* Bp = Bt + ((size_t)bcol * NSTEP + (size_t)kh * NT) * BTILE;

    int ccol0 = bcol * 128 + wc * 64 + (lane & 15);

    f32x4 acc[4][4];
    if (kh == 0) {
        #pragma unroll
        for (int n = 0; n < 4; ++n) {
            float bv = biasT[ccol0 + n * 16];
            #pragma unroll
            for (int m = 0; m < 4; ++m)
                #pragma unroll
                for (int j = 0; j < 4; ++j)
                    acc[m][n][j] = bv;
        }
    } else {
        #pragma unroll
        for (int m = 0; m < 4; ++m)
            #pragma unroll
            for (int n = 0; n < 4; ++n)
                #pragma unroll
                for (int j = 0; j < 4; ++j)
                    acc[m][n][j] = 0.0f;
    }

    #define STAGE(T, SLOT) do {                                               \
        const char* _sa = Ap + (size_t)(T) * BTILE;                           \
        const char* _sb = Bp + (size_t)(T) * BTILE;                           \
        char* _d = lds + (SLOT) * 16384;                                      \
        gload16(_sa + tid * 16,        _d + tid * 16);                        \
        gload16(_sa + tid * 16 + 4096, _d + tid * 16 + 4096);                 \
        gload16(_sb + tid * 16,        _d + 8192 + tid * 16);                 \
        gload16(_sb + tid * 16 + 4096, _d + 8192 + tid * 16 + 4096);          \
    } while (0)

    // prologue: stage tiles 0,1 (8 loads in flight)
    STAGE(0, 0);
    STAGE(1, 1);

    int cs = 0;                                     // compute slot = t % 3
    #pragma unroll 1
    for (int t = 0; t < NT; ++t) {
        if (t < NT - 1) WAITV(4);                   // drains stage(t)
        else            WAITV(0);
        __builtin_amdgcn_s_barrier();               // publish stage(t)
        asm volatile("" ::: "memory");

        if (t + 2 < NT) {
            int ss = cs + 2; if (ss >= 3) ss -= 3;  // (t+2) % 3
            STAGE(t + 2, ss);
        }

        const char* buf = lds + cs * 16384;
        const u16* As = (const u16*)buf;
        const u16* Bs = As + 4096;
        bf16x8 af[4], bfv[4];
        #pragma unroll
        for (int m = 0; m < 4; ++m)
            af[m] = *(const bf16x8*)(As + (wr * 4 + m) * 512 + lane * 8);
        #pragma unroll
        for (int n = 0; n < 4; ++n)
            bfv[n] = *(const bf16x8*)(Bs + (wc * 4 + n) * 512 + lane * 8);

        __builtin_amdgcn_s_setprio(1);
        #pragma unroll
        for (int m = 0; m < 4; ++m)
            #pragma unroll
            for (int n = 0; n < 4; ++n)
                acc[m][n] = __builtin_amdgcn_mfma_f32_16x16x32_bf16(
                    af[m], bfv[n], acc[m][n], 0, 0, 0);
        __builtin_amdgcn_s_setprio(0);

        ++cs; if (cs >= 3) cs = 0;
    }
    #undef STAGE

    // epilogue: C/D layout col = lane&15, row = (lane>>4)*4 + reg
    int crow0 = brow * 128 + wr * 64 + ((lane >> 4) << 2);
    if (kh == 0) {
        #pragma unroll
        for (int m = 0; m < 4; ++m)
            #pragma unroll
            for (int j = 0; j < 4; ++j) {
                size_t r = (size_t)(crow0 + m * 16 + j);
                float* cp = out + r * OUT_F + ccol0;
                #pragma unroll
                for (int n = 0; n < 4; ++n)
                    cp[n * 16] = acc[m][n][j];
            }
    } else {
        #pragma unroll
        for (int m = 0; m < 4; ++m)
            #pragma unroll
            for (int j = 0; j < 4; ++j) {
                size_t r = (size_t)(crow0 + m * 16 + j);
                u16* cp = p1 + r * OUT_F + ccol0;
                #pragma unroll
                for (int n = 0; n < 4; ++n)
                    cp[n * 16] = f2bf(acc[m][n][j]);
            }
    }
}

// ---------------------------------------------------------------------------
// reduce: out += f32(p1)   (8 elems/thread, vectorized)
// ---------------------------------------------------------------------------
__global__ __launch_bounds__(256) void reduce_kernel(
    float* __restrict__ out, const u16* __restrict__ p1)
{
    int i = (blockIdx.x * 256 + threadIdx.x) * 8;
    u16x8 pv = *(const u16x8*)(p1 + i);
    float4 a0 = *(const float4*)(out + i);
    float4 a1 = *(const float4*)(out + i + 4);
    float av[8] = {a0.x, a0.y, a0.z, a0.w, a1.x, a1.y, a1.z, a1.w};
    #pragma unroll
    for (int j = 0; j < 8; ++j)
        av[j] += __uint_as_float(((u32)pv[j]) << 16);
    float4 r0 = {av[0], av[1], av[2], av[3]};
    float4 r1 = {av[4], av[5], av[6], av[7]};
    *(float4*)(out + i)     = r0;
    *(float4*)(out + i + 4) = r1;
}

// Fallback signal if workspace is too small: absmax will read ~12345.
__global__ void sentinel_kernel(float* out, int n) {
    int i = blockIdx.x * 256 + threadIdx.x;
    if (i < n) out[i] = (i == 0) ? 12345.0f : 0.0f;
}

extern "C" void kernel_launch(void* const* d_in, const int* in_sizes, int n_in,
                              void* d_out, int out_size, void* d_ws, size_t ws_size,
                              hipStream_t stream) {
    const float* x    = (const float*)d_in[0];
    const float* sw   = (const float*)d_in[1];
    const float* bw   = (const float*)d_in[2];
    const float* grid = (const float*)d_in[3];
    float* out = (float*)d_out;

    const size_t A_bytes  = (size_t)64 * NSTEP * BTILE;     // 83,886,080
    const size_t B_bytes  = (size_t)8  * NSTEP * BTILE;     // 10,485,760
    const size_t p1_bytes = (size_t)B_DIM * OUT_F * 2;      // 16,777,216
    const size_t bias_bytes = 1024 * sizeof(float);
    if (ws_size < A_bytes + B_bytes + p1_bytes + bias_bytes) {
        sentinel_kernel<<<(out_size + 255) / 256, 256, 0, stream>>>(out, out_size);
        return;
    }

    char*  At    = (char*)d_ws;
    char*  Bt    = (char*)d_ws + A_bytes;
    u16*   p1    = (u16*)((char*)d_ws + A_bytes + B_bytes);
    float* biasT = (float*)((char*)d_ws + A_bytes + B_bytes + p1_bytes);

    prep_kernel<<<4864, 256, 0, stream>>>(x, sw, bw, grid, At, Bt, biasT);
    gemm_half_kernel<<<1024, 256, 0, stream>>>(At, Bt, biasT, out, p1);
    reduce_kernel<<<B_DIM * OUT_F / 2048, 256, 0, stream>>>(out, p1);
}

// Round 18
// 85.865 us; speedup vs baseline: 1.4973x; 1.4973x over previous
//
#include <hip/hip_runtime.h>
#include <hip/hip_bf16.h>
#include <math.h>

#define B_DIM 8192
#define IN_F  1024
#define OUT_F 1024
#define NSTEP 96                     // 32 bf16 tiles (K=1024) + 64 i8 tiles (K=4096)
#define BTILE 8192                   // every step-tile is 8 KB per operand

typedef unsigned short u16;
typedef unsigned int u32;
typedef __attribute__((ext_vector_type(8))) short bf16x8;
typedef __attribute__((ext_vector_type(8))) unsigned short u16x8;
typedef __attribute__((ext_vector_type(16))) char c8x16;
typedef __attribute__((ext_vector_type(4))) int i32x4;
typedef __attribute__((ext_vector_type(4))) float f32x4;

#define GLOBAL_AS __attribute__((address_space(1)))
#define LDS_AS    __attribute__((address_space(3)))

__device__ __forceinline__ void gload16(const void* g, void* l) {
    __builtin_amdgcn_global_load_lds((const GLOBAL_AS unsigned int*)g,
                                     (LDS_AS unsigned int*)l, 16, 0, 0);
}

__device__ __forceinline__ u16 f2bf(float v) {
    u32 u = __float_as_uint(v);
    return (u16)((u + 0x7FFFu + ((u >> 16) & 1u)) >> 16);
}

__device__ __forceinline__ u32 cvt_pk(float lo, float hi) {
    u32 r;
    asm("v_cvt_pk_bf16_f32 %0, %1, %2" : "=v"(r) : "v"(lo), "v"(hi));
    return r;
}

__device__ __forceinline__ float bf2f(u16 v) {
    return __uint_as_float(((u32)v) << 16);
}

// x-space step threshold for grid value gv: smallest f32 T with
// (x >= T) <=> ((double)x > atanh(midpoint(gv, prevfloat(gv)))) —
// replicates a correctly-rounded tanh's interval comparisons.
__device__ __forceinline__ float step_threshold(float gv) {
    float below = nextafterf(gv, -2.0f);
    double mid = 0.5 * ((double)gv + (double)below);
    double t = atanh(mid);
    float Tf = (float)t;
    if (!((double)Tf > t)) Tf = nextafterf(Tf, 3.0f);
    return Tf;
}

// ---------------------------------------------------------------------------
// Operand images. Panel stream per 128 rows/cols: tiles 0..31 = bf16 base
// (128 x 32k x 2B), tiles 32..95 = i8 spline (128 x 64kk x 1B), kk = i*4+s.
// All tiles 8 KB; chunk addressing: tile_base + sub*1024 + lane*16 where
// lane=(fr|q*16): bf16 k = q*8+j (u16), i8 kk = q*16+j (bytes).
// ---------------------------------------------------------------------------
// prep sections by blockIdx:
//   bid 0..255     : pack_B columns (4 cols/block): bias, colmax->scale,
//                    bf16 base strips, i8 spline strips (error-diffusion)
//   bid 256..8447  : pack_A indicator i8 tiles
//   bid 8448..12543: pack_A x bf16 tiles
// ---------------------------------------------------------------------------
__global__ __launch_bounds__(256) void prep_kernel(
    const float* __restrict__ x, const float* __restrict__ sw,
    const float* __restrict__ bw, const float* __restrict__ grid,
    char* __restrict__ At, char* __restrict__ Bt, float* __restrict__ biasT)
{
    __shared__ u16 dsc[4][1024][4];                 // 32 KB: d_s as bf16
    __shared__ float thr[4];

    int bid = blockIdx.x;
    int tid = threadIdx.x;
    int lane = tid & 63;
    int w    = tid >> 6;

    if (bid < 256) {                                // ---- pack_B columns ----
        int o = bid * 4 + w;                        // one col per wave
        int p_b  = o >> 7;
        int colr = o & 127;
        int sub  = colr >> 4;
        int fc   = colr & 15;

        // pass 1: d_s, bias, colmax
        float bias = 0.f, colmax = 0.f;
        #pragma unroll
        for (int it = 0; it < 16; ++it) {
            int i = it * 64 + lane;
            const float* sp = sw + ((size_t)o * IN_F + i) * 8;
            float4 lo = *(const float4*)sp;
            float4 hi = *(const float4*)(sp + 4);
            float c0 = lo.x, c1 = lo.y, c2 = lo.z, c3 = lo.w, c4 = hi.x;
            bias += c0;
            float d0 = c1 - c0, d1 = c2 - c1, d2 = c3 - c2, d3 = c4 - c3;
            colmax = fmaxf(colmax, fmaxf(fmaxf(fabsf(d0), fabsf(d1)),
                                         fmaxf(fabsf(d2), fabsf(d3))));
            dsc[w][i][0] = f2bf(d0); dsc[w][i][1] = f2bf(d1);
            dsc[w][i][2] = f2bf(d2); dsc[w][i][3] = f2bf(d3);
        }
        #pragma unroll
        for (int off = 32; off; off >>= 1) {
            bias  += __shfl_xor(bias, off);
            colmax = fmaxf(colmax, __shfl_xor(colmax, off));
        }
        float scale = (colmax > 1e-30f) ? colmax / 127.0f : 1.0f;
        float inv   = 1.0f / scale;
        if (lane == 0) { biasT[o] = bias; biasT[1024 + o] = scale; }

        // pass 2: i8 spline strips with per-(i) s-prefix error diffusion
        #pragma unroll
        for (int rep = 0; rep < 4; ++rep) {
            int chunk = rep * 64 + lane;            // 0..255
            int ts = chunk >> 2;
            int kq = chunk & 3;
            int ib = ts * 16 + kq * 4;
            c8x16 v;
            #pragma unroll
            for (int ii = 0; ii < 4; ++ii) {
                float carry = 0.f;
                #pragma unroll
                for (int s = 0; s < 4; ++s) {
                    float d = bf2f(dsc[w][ib + ii][s]);
                    float t = d + carry;
                    float qf = rintf(t * inv);
                    qf = fminf(fmaxf(qf, -127.f), 127.f);
                    carry = t - scale * qf;
                    v[ii * 4 + s] = (char)(int)qf;
                }
            }
            *(c8x16*)(Bt + ((size_t)(p_b * NSTEP + 32 + ts)) * BTILE
                      + (size_t)sub * 1024 + (size_t)(kq * 16 + fc) * 16) = v;
        }
        // pass 3: bf16 base strips
        #pragma unroll
        for (int rep = 0; rep < 2; ++rep) {
            int chunk = rep * 64 + lane;            // 0..127
            int tb = chunk >> 2;
            int q  = chunk & 3;
            int i0 = tb * 32 + q * 8;
            const float* bp = bw + (size_t)o * IN_F + i0;
            float4 a = *(const float4*)bp;
            float4 b = *(const float4*)(bp + 4);
            float vv[8] = {a.x, a.y, a.z, a.w, b.x, b.y, b.z, b.w};
            u16x8 s8;
            #pragma unroll
            for (int j = 0; j < 8; ++j) s8[j] = f2bf(vv[j]);
            *(u16x8*)(Bt + ((size_t)(p_b * NSTEP + tb)) * BTILE
                      + (size_t)sub * 1024 + (size_t)(q * 16 + fc) * 16) = s8;
        }
    } else if (bid < 8448) {                        // ---- pack_A indicators ----
        if (tid == 0) {
            #pragma unroll
            for (int k = 0; k < 4; ++k)
                thr[k] = step_threshold(grid[k + 1]);
        }
        __syncthreads();
        float T0 = thr[0], T1 = thr[1], T2 = thr[2], T3 = thr[3];

        int widx = (bid - 256) * 4 + w;             // 0..32767
        int t  = widx & 63;
        int sm = (widx >> 6) & 7;
        int p  = widx >> 9;                         // 0..63
        int fr = lane & 15;
        int kq = lane >> 4;

        int b  = p * 128 + sm * 16 + fr;
        int i0 = t * 16 + kq * 4;
        float4 xv = *(const float4*)(x + (size_t)b * IN_F + i0);
        float xs[4] = {xv.x, xv.y, xv.z, xv.w};

        c8x16 v;
        #pragma unroll
        for (int ii = 0; ii < 4; ++ii) {
            v[ii * 4 + 0] = xs[ii] >= T0 ? 1 : 0;
            v[ii * 4 + 1] = xs[ii] >= T1 ? 1 : 0;
            v[ii * 4 + 2] = xs[ii] >= T2 ? 1 : 0;
            v[ii * 4 + 3] = xs[ii] >= T3 ? 1 : 0;
        }
        *(c8x16*)(At + ((size_t)(p * NSTEP + 32 + t)) * BTILE
                  + (size_t)sm * 1024 + (size_t)lane * 16) = v;
    } else {                                        // ---- pack_A x (bf16) ----
        int widx = (bid - 8448) * 4 + w;            // 0..16383
        int g  = widx & 31;
        int sm = (widx >> 5) & 7;
        int p  = widx >> 8;                         // 0..63
        int fr = lane & 15;
        int q  = lane >> 4;

        int b  = p * 128 + sm * 16 + fr;
        int i0 = g * 32 + q * 8;
        const float* xr = x + (size_t)b * IN_F + i0;
        float4 a0 = *(const float4*)xr;
        float4 a1 = *(const float4*)(xr + 4);
        union { u32 u[4]; u16x8 s; } wpk;
        wpk.u[0] = cvt_pk(a0.x, a0.y);
        wpk.u[1] = cvt_pk(a0.z, a0.w);
        wpk.u[2] = cvt_pk(a1.x, a1.y);
        wpk.u[3] = cvt_pk(a1.z, a1.w);
        *(u16x8*)(At + ((size_t)(p * NSTEP + g)) * BTILE
                  + (size_t)sm * 1024 + (size_t)lane * 16) = wpk.s;
    }
}

// ---------------------------------------------------------------------------
// GEMM (R13 mechanics, 96 tiles): tiles 0..31 bf16 -> facc (bias-init);
// tiles 32..95 i8 -> iacc (i32, exact). 128x128 tile, 4-slot 64KB LDS ring,
// depth-3 prefetch, counted vmcnt (8/4/0), one barrier/tile, setprio.
// 4 waves 2x2; wave = 64x64 out. Epilogue: out = facc + scale_col * iacc.
// ---------------------------------------------------------------------------
#define WAITV(N) asm volatile("s_waitcnt vmcnt(" #N ")" ::: "memory")

__global__ __launch_bounds__(256, 2) void gemm_kernel(
    const char* __restrict__ At, const char* __restrict__ Bt,
    const float* __restrict__ biasT, float* __restrict__ C)
{
    __shared__ __align__(16) char lds[4 * 16384];   // 4-slot ring, 64 KB

    int tid = threadIdx.x;
    int bid = blockIdx.x;                           // 0..511

    int xcd  = bid & 7;
    int slot = bid >> 3;
    int tile = xcd * 64 + slot;
    int brow = tile >> 3;                           // 0..63
    int bcol = tile & 7;                            // 0..7

    int lane = tid & 63;
    int w    = tid >> 6;
    int wr   = w >> 1;
    int wc   = w & 1;

    const char* Ap = At + (size_t)brow * NSTEP * BTILE;
    const char* Bp = Bt + (size_t)bcol * NSTEP * BTILE;

    int ccol0 = bcol * 128 + wc * 64 + (lane & 15);

    f32x4 facc[4][4];
    #pragma unroll
    for (int n = 0; n < 4; ++n) {
        float bv = biasT[ccol0 + n * 16];
        #pragma unroll
        for (int m = 0; m < 4; ++m)
            #pragma unroll
            for (int j = 0; j < 4; ++j)
                facc[m][n][j] = bv;
    }

    #define STAGE(T) do {                                                     \
        const char* _sa = Ap + (size_t)(T) * BTILE;                           \
        const char* _sb = Bp + (size_t)(T) * BTILE;                           \
        char* _d = lds + ((T) & 3) * 16384;                                   \
        gload16(_sa + tid * 16,        _d + tid * 16);                        \
        gload16(_sa + tid * 16 + 4096, _d + tid * 16 + 4096);                 \
        gload16(_sb + tid * 16,        _d + 8192 + tid * 16);                 \
        gload16(_sb + tid * 16 + 4096, _d + 8192 + tid * 16 + 4096);          \
    } while (0)

    STAGE(0); STAGE(1); STAGE(2);

    // ---- loop A: bf16 base tiles 0..31 ----
    #pragma unroll 1
    for (int t = 0; t < 32; ++t) {
        WAITV(8);
        __builtin_amdgcn_s_barrier();
        asm volatile("" ::: "memory");
        STAGE(t + 3);

        const char* buf = lds + (t & 3) * 16384;
        const u16* As = (const u16*)buf;
        const u16* Bs = As + 4096;
        bf16x8 af[4], bfv[4];
        #pragma unroll
        for (int m = 0; m < 4; ++m)
            af[m] = *(const bf16x8*)(As + (wr * 4 + m) * 512 + lane * 8);
        #pragma unroll
        for (int n = 0; n < 4; ++n)
            bfv[n] = *(const bf16x8*)(Bs + (wc * 4 + n) * 512 + lane * 8);

        __builtin_amdgcn_s_setprio(1);
        #pragma unroll
        for (int m = 0; m < 4; ++m)
            #pragma unroll
            for (int n = 0; n < 4; ++n)
                facc[m][n] = __builtin_amdgcn_mfma_f32_16x16x32_bf16(
                    af[m], bfv[n], facc[m][n], 0, 0, 0);
        __builtin_amdgcn_s_setprio(0);
    }

    // ---- loop B: i8 spline tiles 32..95 ----
    i32x4 iacc[4][4];
    #pragma unroll
    for (int m = 0; m < 4; ++m)
        #pragma unroll
        for (int n = 0; n < 4; ++n)
            #pragma unroll
            for (int j = 0; j < 4; ++j)
                iacc[m][n][j] = 0;

    #pragma unroll 1
    for (int t = 32; t < NSTEP; ++t) {
        if (t < NSTEP - 2)       WAITV(8);
        else if (t == NSTEP - 2) WAITV(4);
        else                     WAITV(0);
        __builtin_amdgcn_s_barrier();
        asm volatile("" ::: "memory");
        if (t + 3 < NSTEP) STAGE(t + 3);

        const char* buf = lds + (t & 3) * 16384;
        i32x4 ai[4], bi[4];
        #pragma unroll
        for (int m = 0; m < 4; ++m)
            ai[m] = *(const i32x4*)(buf + (wr * 4 + m) * 1024 + lane * 16);
        #pragma unroll
        for (int n = 0; n < 4; ++n)
            bi[n] = *(const i32x4*)(buf + 8192 + (wc * 4 + n) * 1024 + lane * 16);

        __builtin_amdgcn_s_setprio(1);
        #pragma unroll
        for (int m = 0; m < 4; ++m)
            #pragma unroll
            for (int n = 0; n < 4; ++n)
                iacc[m][n] = __builtin_amdgcn_mfma_i32_16x16x64_i8(
                    ai[m], bi[n], iacc[m][n], 0, 0, 0);
        __builtin_amdgcn_s_setprio(0);
    }
    #undef STAGE

    // epilogue: C/D layout col = lane&15, row = (lane>>4)*4 + reg
    float sc[4];
    #pragma unroll
    for (int n = 0; n < 4; ++n) sc[n] = biasT[1024 + ccol0 + n * 16];
    int crow0 = brow * 128 + wr * 64 + ((lane >> 4) << 2);
    #pragma unroll
    for (int m = 0; m < 4; ++m)
        #pragma unroll
        for (int j = 0; j < 4; ++j) {
            size_t r = (size_t)(crow0 + m * 16 + j);
            float* cp = C + r * OUT_F + ccol0;
            #pragma unroll
            for (int n = 0; n < 4; ++n)
                cp[n * 16] = facc[m][n][j] + sc[n] * (float)iacc[m][n][j];
        }
}

// Fallback signal if workspace is too small: absmax will read ~12345.
__global__ void sentinel_kernel(float* out, int n) {
    int i = blockIdx.x * 256 + threadIdx.x;
    if (i < n) out[i] = (i == 0) ? 12345.0f : 0.0f;
}

extern "C" void kernel_launch(void* const* d_in, const int* in_sizes, int n_in,
                              void* d_out, int out_size, void* d_ws, size_t ws_size,
                              hipStream_t stream) {
    const float* x    = (const float*)d_in[0];
    const float* sw   = (const float*)d_in[1];
    const float* bw   = (const float*)d_in[2];
    const float* grid = (const float*)d_in[3];
    float* out = (float*)d_out;

    const size_t A_bytes = (size_t)64 * NSTEP * BTILE;  // 50,331,648
    const size_t B_bytes = (size_t)8  * NSTEP * BTILE;  //  6,291,456
    const size_t bias_bytes = 2048 * sizeof(float);
    if (ws_size < A_bytes + B_bytes + bias_bytes) {
        sentinel_kernel<<<(out_size + 255) / 256, 256, 0, stream>>>(out, out_size);
        return;
    }

    char*  At    = (char*)d_ws;
    char*  Bt    = (char*)d_ws + A_bytes;
    float* biasT = (float*)((char*)d_ws + A_bytes + B_bytes);

    prep_kernel<<<12544, 256, 0, stream>>>(x, sw, bw, grid, At, Bt, biasT);
    gemm_kernel<<<512, 256, 0, stream>>>(At, Bt, biasT, out);
}

// Round 19
// 72.210 us; speedup vs baseline: 1.7805x; 1.1891x over previous
//
#include <hip/hip_runtime.h>
#include <hip/hip_bf16.h>
#include <math.h>

#define B_DIM 8192
#define IN_F  1024
#define OUT_F 1024
#define NSTEP 96                     // 32 bf16 tiles (K=1024) + 64 i8 tiles (K=4096)
#define BTILE 8192                   // every step-tile is 8 KB per operand

typedef unsigned short u16;
typedef unsigned int u32;
typedef __attribute__((ext_vector_type(8))) short bf16x8;
typedef __attribute__((ext_vector_type(8))) unsigned short u16x8;
typedef __attribute__((ext_vector_type(16))) char c8x16;
typedef __attribute__((ext_vector_type(4))) int i32x4;
typedef __attribute__((ext_vector_type(4))) float f32x4;

#define GLOBAL_AS __attribute__((address_space(1)))
#define LDS_AS    __attribute__((address_space(3)))

__device__ __forceinline__ void gload16(const void* g, void* l) {
    __builtin_amdgcn_global_load_lds((const GLOBAL_AS unsigned int*)g,
                                     (LDS_AS unsigned int*)l, 16, 0, 0);
}

__device__ __forceinline__ u16 f2bf(float v) {
    u32 u = __float_as_uint(v);
    return (u16)((u + 0x7FFFu + ((u >> 16) & 1u)) >> 16);
}

__device__ __forceinline__ u32 cvt_pk(float lo, float hi) {
    u32 r;
    asm("v_cvt_pk_bf16_f32 %0, %1, %2" : "=v"(r) : "v"(lo), "v"(hi));
    return r;
}

__device__ __forceinline__ float bf2f(u16 v) {
    return __uint_as_float(((u32)v) << 16);
}

// x-space step threshold for grid value gv: smallest f32 T with
// (x >= T) <=> ((double)x > atanh(midpoint(gv, prevfloat(gv)))) —
// replicates a correctly-rounded tanh's interval comparisons.
__device__ __forceinline__ float step_threshold(float gv) {
    float below = nextafterf(gv, -2.0f);
    double mid = 0.5 * ((double)gv + (double)below);
    double t = atanh(mid);
    float Tf = (float)t;
    if (!((double)Tf > t)) Tf = nextafterf(Tf, 3.0f);
    return Tf;
}

// ---------------------------------------------------------------------------
// Operand images. Panel stream per 128 rows/cols: tiles 0..31 = bf16 base
// (128 x 32k x 2B), tiles 32..95 = i8 spline (128 x 64kk x 1B), kk = i*4+s.
// All tiles 8 KB; chunk addressing: tile_base + sub*1024 + lane*16 where
// lane=(fr|q*16): bf16 k = q*8+j (u16), i8 kk = q*16+j (bytes).
// ---------------------------------------------------------------------------
// prep sections by blockIdx:
//   bid 0..255    : pack_B columns (4 cols/block): bias, colmax->scale,
//                   bf16 base strips, i8 spline strips (error-diffusion)
//   bid 256..4351 : pack_A merged — ONE x read per element emits both the
//                   bf16 chunk (tile g) and both indicator chunks
//                   (tile 32+2g+(q>>1), kq' = (q&1)*2+c)  [saves 32 MB]
// ---------------------------------------------------------------------------
__global__ __launch_bounds__(256) void prep_kernel(
    const float* __restrict__ x, const float* __restrict__ sw,
    const float* __restrict__ bw, const float* __restrict__ grid,
    char* __restrict__ At, char* __restrict__ Bt, float* __restrict__ biasT)
{
    __shared__ u16 dsc[4][1024][4];                 // 32 KB: d_s as bf16
    __shared__ float thr[4];

    int bid = blockIdx.x;
    int tid = threadIdx.x;
    int lane = tid & 63;
    int w    = tid >> 6;

    if (bid < 256) {                                // ---- pack_B columns ----
        int o = bid * 4 + w;                        // one col per wave
        int p_b  = o >> 7;
        int colr = o & 127;
        int sub  = colr >> 4;
        int fc   = colr & 15;

        // pass 1: d_s, bias, colmax
        float bias = 0.f, colmax = 0.f;
        #pragma unroll
        for (int it = 0; it < 16; ++it) {
            int i = it * 64 + lane;
            const float* sp = sw + ((size_t)o * IN_F + i) * 8;
            float4 lo = *(const float4*)sp;
            float4 hi = *(const float4*)(sp + 4);
            float c0 = lo.x, c1 = lo.y, c2 = lo.z, c3 = lo.w, c4 = hi.x;
            bias += c0;
            float d0 = c1 - c0, d1 = c2 - c1, d2 = c3 - c2, d3 = c4 - c3;
            colmax = fmaxf(colmax, fmaxf(fmaxf(fabsf(d0), fabsf(d1)),
                                         fmaxf(fabsf(d2), fabsf(d3))));
            dsc[w][i][0] = f2bf(d0); dsc[w][i][1] = f2bf(d1);
            dsc[w][i][2] = f2bf(d2); dsc[w][i][3] = f2bf(d3);
        }
        #pragma unroll
        for (int off = 32; off; off >>= 1) {
            bias  += __shfl_xor(bias, off);
            colmax = fmaxf(colmax, __shfl_xor(colmax, off));
        }
        float scale = (colmax > 1e-30f) ? colmax / 127.0f : 1.0f;
        float inv   = 1.0f / scale;
        if (lane == 0) { biasT[o] = bias; biasT[1024 + o] = scale; }

        // pass 2: i8 spline strips with per-(i) s-prefix error diffusion
        #pragma unroll
        for (int rep = 0; rep < 4; ++rep) {
            int chunk = rep * 64 + lane;            // 0..255
            int ts = chunk >> 2;
            int kq = chunk & 3;
            int ib = ts * 16 + kq * 4;
            c8x16 v;
            #pragma unroll
            for (int ii = 0; ii < 4; ++ii) {
                float carry = 0.f;
                #pragma unroll
                for (int s = 0; s < 4; ++s) {
                    float d = bf2f(dsc[w][ib + ii][s]);
                    float t = d + carry;
                    float qf = rintf(t * inv);
                    qf = fminf(fmaxf(qf, -127.f), 127.f);
                    carry = t - scale * qf;
                    v[ii * 4 + s] = (char)(int)qf;
                }
            }
            *(c8x16*)(Bt + ((size_t)(p_b * NSTEP + 32 + ts)) * BTILE
                      + (size_t)sub * 1024 + (size_t)(kq * 16 + fc) * 16) = v;
        }
        // pass 3: bf16 base strips
        #pragma unroll
        for (int rep = 0; rep < 2; ++rep) {
            int chunk = rep * 64 + lane;            // 0..127
            int tb = chunk >> 2;
            int q  = chunk & 3;
            int i0 = tb * 32 + q * 8;
            const float* bp = bw + (size_t)o * IN_F + i0;
            float4 a = *(const float4*)bp;
            float4 b = *(const float4*)(bp + 4);
            float vv[8] = {a.x, a.y, a.z, a.w, b.x, b.y, b.z, b.w};
            u16x8 s8;
            #pragma unroll
            for (int j = 0; j < 8; ++j) s8[j] = f2bf(vv[j]);
            *(u16x8*)(Bt + ((size_t)(p_b * NSTEP + tb)) * BTILE
                      + (size_t)sub * 1024 + (size_t)(q * 16 + fc) * 16) = s8;
        }
    } else {                                        // ---- pack_A merged ----
        if (tid == 0) {
            #pragma unroll
            for (int k = 0; k < 4; ++k)
                thr[k] = step_threshold(grid[k + 1]);   // -0.6,-0.2,0.2,0.6
        }
        __syncthreads();
        float T0 = thr[0], T1 = thr[1], T2 = thr[2], T3 = thr[3];

        int widx = (bid - 256) * 4 + w;             // 0..16383
        int g  = widx & 31;
        int sm = (widx >> 5) & 7;
        int p  = widx >> 8;                         // 0..63
        int fr = lane & 15;
        int q  = lane >> 4;

        int b  = p * 128 + sm * 16 + fr;
        int i0 = g * 32 + q * 8;
        const float* xr = x + (size_t)b * IN_F + i0;
        float4 a0 = *(const float4*)xr;
        float4 a1 = *(const float4*)(xr + 4);
        float xs[8] = {a0.x, a0.y, a0.z, a0.w, a1.x, a1.y, a1.z, a1.w};

        // bf16 x chunk -> tile g
        union { u32 u[4]; u16x8 s; } wpk;
        wpk.u[0] = cvt_pk(xs[0], xs[1]);
        wpk.u[1] = cvt_pk(xs[2], xs[3]);
        wpk.u[2] = cvt_pk(xs[4], xs[5]);
        wpk.u[3] = cvt_pk(xs[6], xs[7]);
        *(u16x8*)(At + ((size_t)(p * NSTEP + g)) * BTILE
                  + (size_t)sm * 1024 + (size_t)lane * 16) = wpk.s;

        // indicator chunks -> tile 32 + 2g + (q>>1), kq' = (q&1)*2 + c
        // i = 32g + (q>>1)*16 + (q&1)*8 + c*4 + (j>>2) == i0 + c*4 + (j>>2)
        int t = 2 * g + (q >> 1);
        size_t tbase = ((size_t)(p * NSTEP + 32 + t)) * BTILE
                     + (size_t)sm * 1024;
        #pragma unroll
        for (int c = 0; c < 2; ++c) {
            int kq2 = (q & 1) * 2 + c;
            c8x16 v;
            #pragma unroll
            for (int j = 0; j < 16; ++j) {
                float xv = xs[c * 4 + (j >> 2)];
                int s = j & 3;
                float T = (s == 0) ? T0 : (s == 1) ? T1 : (s == 2) ? T2 : T3;
                v[j] = xv >= T ? 1 : 0;
            }
            *(c8x16*)(At + tbase + (size_t)(kq2 * 16 + fr) * 16) = v;
        }
    }
}

// ---------------------------------------------------------------------------
// GEMM (R18 verbatim — measured 53.9us): tiles 0..31 bf16 -> facc
// (bias-init); tiles 32..95 i8 -> iacc (i32, exact). 128x128 tile, 4-slot
// 64KB LDS ring, depth-3 prefetch, counted vmcnt (8/4/0), one barrier/tile,
// setprio. 4 waves 2x2; wave = 64x64 out.
// Epilogue: out = facc + scale_col * iacc.
// ---------------------------------------------------------------------------
#define WAITV(N) asm volatile("s_waitcnt vmcnt(" #N ")" ::: "memory")

__global__ __launch_bounds__(256, 2) void gemm_kernel(
    const char* __restrict__ At, const char* __restrict__ Bt,
    const float* __restrict__ biasT, float* __restrict__ C)
{
    __shared__ __align__(16) char lds[4 * 16384];   // 4-slot ring, 64 KB

    int tid = threadIdx.x;
    int bid = blockIdx.x;                           // 0..511

    int xcd  = bid & 7;
    int slot = bid >> 3;
    int tile = xcd * 64 + slot;
    int brow = tile >> 3;                           // 0..63
    int bcol = tile & 7;                            // 0..7

    int lane = tid & 63;
    int w    = tid >> 6;
    int wr   = w >> 1;
    int wc   = w & 1;

    const char* Ap = At + (size_t)brow * NSTEP * BTILE;
    const char* Bp = Bt + (size_t)bcol * NSTEP * BTILE;

    int ccol0 = bcol * 128 + wc * 64 + (lane & 15);

    f32x4 facc[4][4];
    #pragma unroll
    for (int n = 0; n < 4; ++n) {
        float bv = biasT[ccol0 + n * 16];
        #pragma unroll
        for (int m = 0; m < 4; ++m)
            #pragma unroll
            for (int j = 0; j < 4; ++j)
                facc[m][n][j] = bv;
    }

    #define STAGE(T) do {                                                     \
        const char* _sa = Ap + (size_t)(T) * BTILE;                           \
        const char* _sb = Bp + (size_t)(T) * BTILE;                           \
        char* _d = lds + ((T) & 3) * 16384;                                   \
        gload16(_sa + tid * 16,        _d + tid * 16);                        \
        gload16(_sa + tid * 16 + 4096, _d + tid * 16 + 4096);                 \
        gload16(_sb + tid * 16,        _d + 8192 + tid * 16);                 \
        gload16(_sb + tid * 16 + 4096, _d + 8192 + tid * 16 + 4096);          \
    } while (0)

    STAGE(0); STAGE(1); STAGE(2);

    // ---- loop A: bf16 base tiles 0..31 ----
    #pragma unroll 1
    for (int t = 0; t < 32; ++t) {
        WAITV(8);
        __builtin_amdgcn_s_barrier();
        asm volatile("" ::: "memory");
        STAGE(t + 3);

        const char* buf = lds + (t & 3) * 16384;
        const u16* As = (const u16*)buf;
        const u16* Bs = As + 4096;
        bf16x8 af[4], bfv[4];
        #pragma unroll
        for (int m = 0; m < 4; ++m)
            af[m] = *(const bf16x8*)(As + (wr * 4 + m) * 512 + lane * 8);
        #pragma unroll
        for (int n = 0; n < 4; ++n)
            bfv[n] = *(const bf16x8*)(Bs + (wc * 4 + n) * 512 + lane * 8);

        __builtin_amdgcn_s_setprio(1);
        #pragma unroll
        for (int m = 0; m < 4; ++m)
            #pragma unroll
            for (int n = 0; n < 4; ++n)
                facc[m][n] = __builtin_amdgcn_mfma_f32_16x16x32_bf16(
                    af[m], bfv[n], facc[m][n], 0, 0, 0);
        __builtin_amdgcn_s_setprio(0);
    }

    // ---- loop B: i8 spline tiles 32..95 ----
    i32x4 iacc[4][4];
    #pragma unroll
    for (int m = 0; m < 4; ++m)
        #pragma unroll
        for (int n = 0; n < 4; ++n)
            #pragma unroll
            for (int j = 0; j < 4; ++j)
                iacc[m][n][j] = 0;

    #pragma unroll 1
    for (int t = 32; t < NSTEP; ++t) {
        if (t < NSTEP - 2)       WAITV(8);
        else if (t == NSTEP - 2) WAITV(4);
        else                     WAITV(0);
        __builtin_amdgcn_s_barrier();
        asm volatile("" ::: "memory");
        if (t + 3 < NSTEP) STAGE(t + 3);

        const char* buf = lds + (t & 3) * 16384;
        i32x4 ai[4], bi[4];
        #pragma unroll
        for (int m = 0; m < 4; ++m)
            ai[m] = *(const i32x4*)(buf + (wr * 4 + m) * 1024 + lane * 16);
        #pragma unroll
        for (int n = 0; n < 4; ++n)
            bi[n] = *(const i32x4*)(buf + 8192 + (wc * 4 + n) * 1024 + lane * 16);

        __builtin_amdgcn_s_setprio(1);
        #pragma unroll
        for (int m = 0; m < 4; ++m)
            #pragma unroll
            for (int n = 0; n < 4; ++n)
                iacc[m][n] = __builtin_amdgcn_mfma_i32_16x16x64_i8(
                    ai[m], bi[n], iacc[m][n], 0, 0, 0);
        __builtin_amdgcn_s_setprio(0);
    }
    #undef STAGE

    // epilogue: C/D layout col = lane&15, row = (lane>>4)*4 + reg
    float sc[4];
    #pragma unroll
    for (int n = 0; n < 4; ++n) sc[n] = biasT[1024 + ccol0 + n * 16];
    int crow0 = brow * 128 + wr * 64 + ((lane >> 4) << 2);
    #pragma unroll
    for (int m = 0; m < 4; ++m)
        #pragma unroll
        for (int j = 0; j < 4; ++j) {
            size_t r = (size_t)(crow0 + m * 16 + j);
            float* cp = C + r * OUT_F + ccol0;
            #pragma unroll
            for (int n = 0; n < 4; ++n)
                cp[n * 16] = facc[m][n][j] + sc[n] * (float)iacc[m][n][j];
        }
}

// Fallback signal if workspace is too small: absmax will read ~12345.
__global__ void sentinel_kernel(float* out, int n) {
    int i = blockIdx.x * 256 + threadIdx.x;
    if (i < n) out[i] = (i == 0) ? 12345.0f : 0.0f;
}

extern "C" void kernel_launch(void* const* d_in, const int* in_sizes, int n_in,
                              void* d_out, int out_size, void* d_ws, size_t ws_size,
                              hipStream_t stream) {
    const float* x    = (const float*)d_in[0];
    const float* sw   = (const float*)d_in[1];
    const float* bw   = (const float*)d_in[2];
    const float* grid = (const float*)d_in[3];
    float* out = (float*)d_out;

    const size_t A_bytes = (size_t)64 * NSTEP * BTILE;  // 50,331,648
    const size_t B_bytes = (size_t)8  * NSTEP * BTILE;  //  6,291,456
    const size_t bias_bytes = 2048 * sizeof(float);
    if (ws_size < A_bytes + B_bytes + bias_bytes) {
        sentinel_kernel<<<(out_size + 255) / 256, 256, 0, stream>>>(out, out_size);
        return;
    }

    char*  At    = (char*)d_ws;
    char*  Bt    = (char*)d_ws + A_bytes;
    float* biasT = (float*)((char*)d_ws + A_bytes + B_bytes);

    prep_kernel<<<4352, 256, 0, stream>>>(x, sw, bw, grid, At, Bt, biasT);
    gemm_kernel<<<512, 256, 0, stream>>>(At, Bt, biasT, out);
}